// Round 10
// baseline (7250.440 us; speedup 1.0000x reference)
//
#include <hip/hip_runtime.h>
#include <cstdint>

#define NPTS 32768
#define DIM  256
#define NK   128
#define NITER 100
#define NBLK 256
#define NTHR 1024
#define PAD  33

typedef unsigned short ushort_t;
typedef unsigned long long ull_t;
typedef __attribute__((ext_vector_type(8))) short s8v;   // 8 bf16 in 4 VGPRs
typedef __attribute__((ext_vector_type(4))) float f4v;   // MFMA accumulator

__device__ __forceinline__ unsigned short f2bf(float f) {
  unsigned u = __float_as_uint(f);
  u += 0x7fffu + ((u >> 16) & 1u);      // RTNE
  return (unsigned short)(u >> 16);
}
__device__ __forceinline__ float bf2f(unsigned short b) {
  return __uint_as_float(((unsigned)b) << 16);
}

// agent-scope (LLC-coherent) accesses — bypass non-coherent L1/L2, so NO
// __threadfence is needed for data moved through them (proven R8/R9).
__device__ __forceinline__ void cstore(float* p, float v) {
  __hip_atomic_store(p, v, __ATOMIC_RELAXED, __HIP_MEMORY_SCOPE_AGENT);
}
__device__ __forceinline__ float cload(const float* p) {
  return __hip_atomic_load(p, __ATOMIC_RELAXED, __HIP_MEMORY_SCOPE_AGENT);
}
__device__ __forceinline__ void cstorei(int* p, int v) {
  __hip_atomic_store(p, v, __ATOMIC_RELAXED, __HIP_MEMORY_SCOPE_AGENT);
}
__device__ __forceinline__ int cloadi(const int* p) {
  return __hip_atomic_load(p, __ATOMIC_RELAXED, __HIP_MEMORY_SCOPE_AGENT);
}
__device__ __forceinline__ void cstore64(ull_t* p, ull_t v) {
  __hip_atomic_store(p, v, __ATOMIC_RELAXED, __HIP_MEMORY_SCOPE_AGENT);
}
__device__ __forceinline__ ull_t cload64(const ull_t* p) {
  return __hip_atomic_load(p, __ATOMIC_RELAXED, __HIP_MEMORY_SCOPE_AGENT);
}

// Stage one 32KB half-D x tile via global_load_lds (linear LDS dest,
// pre-swizzled global source). LDS[G] = global[G ^ (row&7)], 16B granules.
// 1024 threads: 2 granules each.
__device__ __forceinline__ void stage4(const ushort_t* __restrict__ src, s8v* buf, int h, int t) {
  const int lane = t & 63;
  const int wb = (t >> 6) << 6;           // wave-uniform base granule
#pragma unroll
  for (int i = 0; i < 2; ++i) {
    const int Gb = i * 1024 + wb;
    const int G  = Gb + lane;
    const int Gs = G ^ ((G >> 4) & 7);
    const char* ga = (const char*)src + (G >> 4) * 512 + h * 256 + (Gs & 15) * 16;
    __builtin_amdgcn_global_load_lds(
        (const __attribute__((address_space(1))) void*)ga,
        (__attribute__((address_space(3))) void*)((char*)buf + Gb * 16),
        16, 0, 0);
  }
}

// Stage centroid hi/lo half-D tiles from the packed coherent image.
// cpk[k*128 + u] = dims {2u,2u+1}: hh0 | ll0<<16 | hh1<<32 | ll1<<48.
__device__ __forceinline__ void stage_c(const ull_t* __restrict__ cpk,
                                        s8v* bh, s8v* bl, int h, int t) {
#pragma unroll
  for (int i = 0; i < 2; ++i) {
    const int G = i * NTHR + t;           // granule id [0,2048)
    const int k = G >> 4, gcol = G & 15;
    const int sc2 = gcol ^ (k & 7);       // swizzled source column
    const ull_t* src = cpk + (size_t)k * 128 + h * 64 + sc2 * 4;
    ull_t w0 = cload64(src + 0), w1 = cload64(src + 1);
    ull_t w2 = cload64(src + 2), w3 = cload64(src + 3);
    s8v vh, vl;
    vh[0] = (short)w0; vl[0] = (short)(w0 >> 16); vh[1] = (short)(w0 >> 32); vl[1] = (short)(w0 >> 48);
    vh[2] = (short)w1; vl[2] = (short)(w1 >> 16); vh[3] = (short)(w1 >> 32); vl[3] = (short)(w1 >> 48);
    vh[4] = (short)w2; vl[4] = (short)(w2 >> 16); vh[5] = (short)(w2 >> 32); vl[5] = (short)(w2 >> 48);
    vh[6] = (short)w3; vl[6] = (short)(w3 >> 16); vh[7] = (short)(w3 >> 32); vl[7] = (short)(w3 >> 48);
    *(s8v*)((char*)bh + G * 16) = vh;
    *(s8v*)((char*)bl + G * 16) = vl;
  }
}

// ---- all-to-all 1-hop grid barrier (proven R9) ----
__device__ __forceinline__ void gbar(unsigned* flags, unsigned gen) {
  __syncthreads();
  if (threadIdx.x == 0)
    __hip_atomic_store(&flags[blockIdx.x * 16], gen, __ATOMIC_RELAXED, __HIP_MEMORY_SCOPE_AGENT);
  if (threadIdx.x < NBLK) {
    while (__hip_atomic_load(&flags[threadIdx.x * 16], __ATOMIC_RELAXED, __HIP_MEMORY_SCOPE_AGENT) < gen)
      __builtin_amdgcn_s_sleep(1);
  }
  asm volatile("" ::: "memory");
  __syncthreads();
}
// barrier that issues next GEMM's x half-0 DMA prefetch inside the window
__device__ __forceinline__ void gbar_pf(unsigned* flags, unsigned gen,
    const ushort_t* xhb, const ushort_t* xlb, s8v (*bufs)[2048], int t) {
  __syncthreads();
  stage4(xhb, bufs[0], 0, t);             // own immutable tile: race-free
  stage4(xlb, bufs[1], 0, t);
  if (t == 0)
    __hip_atomic_store(&flags[blockIdx.x * 16], gen, __ATOMIC_RELAXED, __HIP_MEMORY_SCOPE_AGENT);
  if (t < NBLK) {
    while (__hip_atomic_load(&flags[t * 16], __ATOMIC_RELAXED, __HIP_MEMORY_SCOPE_AGENT) < gen)
      __builtin_amdgcn_s_sleep(1);
  }
  asm volatile("" ::: "memory");
  __syncthreads();
}

struct SMa {
  s8v bufs[4][2048];        // XH, XL, CH, CL half-D tiles, 32 KB each = 128 KB
  float cns[NK];
  float redd[NK * 4];
  int   redk[NK * 4];
  float gmaxs[NK];
  float labvs[NK];
  int   labis[NK];
};
union ScU {                 // phase-exclusive scratch (16.9 KB)
  float accB[NK * PAD];     // phase B accumulator
  float red4[1024];         // phase C: 4 x 256 dim-partials
  float redcn[1024];        // tree-reduce scratch (aliases red4; sequenced)
};

// 16-wave (4x4) 3-pass hi/lo bf16 MFMA GEMM: acc[i][j][r] = x_p . c_k.
// Each wave: 32 points x 32 clusters. bufs[0..1] half-0 prefetched by gbar_pf.
__device__ __forceinline__ void gemm_core(
    SMa& sm, int t,
    const ushort_t* __restrict__ xhb, const ushort_t* __restrict__ xlb,
    const ull_t* __restrict__ cpk, const float* __restrict__ cn, f4v (&acc)[2][2]) {
  const int lane = t & 63;
  const int w    = t >> 6;
  const int wr   = w >> 2, wc = w & 3;    // 4x4 wave grid
  const int g    = lane >> 4, lr = lane & 15;

  if (t < NK) sm.cns[t] = cload(&cn[t]);

  const f4v zero = {0.f, 0.f, 0.f, 0.f};
#pragma unroll
  for (int i = 0; i < 2; ++i)
#pragma unroll
    for (int j = 0; j < 2; ++j) acc[i][j] = zero;

  const int swz = (lr & 7) << 4;
  int a_off[2], b_off[2];
#pragma unroll
  for (int i = 0; i < 2; ++i) a_off[i] = (wr * 32 + i * 16 + lr) * 256 + g * 16;
#pragma unroll
  for (int j = 0; j < 2; ++j) b_off[j] = (wc * 32 + j * 16 + lr) * 256 + g * 16;

  for (int h = 0; h < 2; ++h) {           // two D-halves of 128
    if (h == 1) {                         // issue DMA first for overlap
      stage4(xhb, sm.bufs[0], 1, t);
      stage4(xlb, sm.bufs[1], 1, t);
    }
    stage_c(cpk, sm.bufs[2], sm.bufs[3], h, t);
    __syncthreads();                      // DMA + cloads + ds_writes landed
#pragma unroll
    for (int kk = 0; kk < 4; ++kk) {      // K=128 per half, 4 steps of 32
      s8v ah[2], al[2], bh[2], bl[2];
#pragma unroll
      for (int i = 0; i < 2; ++i) {
        int o = (a_off[i] + kk * 64) ^ swz;
        ah[i] = *(const s8v*)((const char*)sm.bufs[0] + o);
        al[i] = *(const s8v*)((const char*)sm.bufs[1] + o);
      }
#pragma unroll
      for (int j = 0; j < 2; ++j) {
        int o = (b_off[j] + kk * 64) ^ swz;
        bh[j] = *(const s8v*)((const char*)sm.bufs[2] + o);
        bl[j] = *(const s8v*)((const char*)sm.bufs[3] + o);
      }
#pragma unroll
      for (int i = 0; i < 2; ++i)
#pragma unroll
        for (int j = 0; j < 2; ++j) {
          acc[i][j] = __builtin_amdgcn_mfma_f32_16x16x32_bf16(ah[i], bh[j], acc[i][j], 0, 0, 0);
          acc[i][j] = __builtin_amdgcn_mfma_f32_16x16x32_bf16(ah[i], bl[j], acc[i][j], 0, 0, 0);
          acc[i][j] = __builtin_amdgcn_mfma_f32_16x16x32_bf16(al[i], bh[j], acc[i][j], 0, 0, 0);
        }
    }
    if (h == 0) __syncthreads();          // half-0 reads done before overwrite
  }
}

__global__ __launch_bounds__(NTHR, 1) void kmeans_fused(
    const float* __restrict__ x, const int* __restrict__ init_idx,
    ushort_t* __restrict__ xh, ushort_t* __restrict__ xl,
    ull_t* __restrict__ cpk, float* __restrict__ cn, int* __restrict__ ids,
    float* __restrict__ psum, float* __restrict__ pcnt,
    float* __restrict__ outp, unsigned* __restrict__ flags,
    float* __restrict__ out) {
  __shared__ SMa sm;
  __shared__ ScU sc;
  __shared__ int idslB[1024];
  __shared__ int cntB[NK];
  __shared__ ushort_t hsm[DIM], lsm[DIM];
  __shared__ float cntsh;

  const int b = blockIdx.x;
  const int t = threadIdx.x;
  const int lane = t & 63;
  const int w  = t >> 6;
  const int wr = w >> 2, wc = w & 3;
  const int g  = lane >> 4, lr = lane & 15;
  const int pbase = b * 128;
  const ushort_t* xhb = xh + (size_t)pbase * DIM;
  const ushort_t* xlb = xl + (size_t)pbase * DIM;
  unsigned gen = 1;

  // ---------------- prep: x -> bf16 hi/lo images (own tile only) ----------------
  for (int i = 0; i < 4; ++i) {
    int gg = b * 4096 + i * NTHR + t;
    const float4* src = (const float4*)x + gg * 2;
    float4 fa = src[0], fb = src[1];
    float vv[8] = {fa.x, fa.y, fa.z, fa.w, fb.x, fb.y, fb.z, fb.w};
    s8v vh, vl;
#pragma unroll
    for (int j = 0; j < 8; ++j) {
      unsigned short hh = f2bf(vv[j]);
      vh[j] = (short)hh;
      vl[j] = (short)f2bf(vv[j] - bf2f(hh));
    }
    ((s8v*)xh)[gg] = vh;
    ((s8v*)xl)[gg] = vl;
  }

  // ---------------- init: c0 = x[init_idx] -> packed image + cn ----------------
  if (b < NK) {
    float eff = 0.f;
    if (t < DIM) {
      float v = x[init_idx[b] * DIM + t];
      unsigned short hh = f2bf(v);
      unsigned short ll = f2bf(v - bf2f(hh));
      hsm[t] = hh; lsm[t] = ll;
      eff = bf2f(hh) + bf2f(ll);
    }
    __syncthreads();
    sc.redcn[t] = (t < DIM) ? eff * eff : 0.f;
    if (t < NK) {
      ull_t wv = (ull_t)hsm[2 * t] | ((ull_t)lsm[2 * t] << 16)
               | ((ull_t)hsm[2 * t + 1] << 32) | ((ull_t)lsm[2 * t + 1] << 48);
      cstore64(&cpk[(size_t)b * 128 + t], wv);
    }
    __syncthreads();
    for (int s = 512; s > 0; s >>= 1) { if (t < s) sc.redcn[t] += sc.redcn[t + s]; __syncthreads(); }
    if (t == 0) cstore(&cn[b], sc.redcn[0]);
  }
  gbar_pf(flags, gen, xhb, xlb, sm.bufs, t); ++gen;

  // ---------------- main loop ----------------
  for (int it = 0; it < NITER; ++it) {
    // ---- phase A: assign; ids -> LLC ----
    {
      f4v acc[2][2];
      gemm_core(sm, t, xhb, xlb, cpk, cn, acc);
#pragma unroll
      for (int i = 0; i < 2; ++i) {
#pragma unroll
        for (int r = 0; r < 4; ++r) {
          int prow = wr * 32 + i * 16 + g * 4 + r;
          float bd = 1e30f; int bk = 0;
#pragma unroll
          for (int j = 0; j < 2; ++j) {
            int col = wc * 32 + j * 16 + lr;
            float s = sm.cns[col] - 2.f * acc[i][j][r];
            if (s < bd || (s == bd && col < bk)) { bd = s; bk = col; }
          }
#pragma unroll
          for (int msk = 1; msk < 16; msk <<= 1) {
            float od = __shfl_xor(bd, msk, 64);
            int   ok = __shfl_xor(bk, msk, 64);
            if (od < bd || (od == bd && ok < bk)) { bd = od; bk = ok; }
          }
          if (lr == 0) { sm.redd[prow * 4 + wc] = bd; sm.redk[prow * 4 + wc] = bk; }
        }
      }
      __syncthreads();
      if (t < NK) {
        float bd = sm.redd[t * 4]; int bk = sm.redk[t * 4];
#pragma unroll
        for (int q = 1; q < 4; ++q) {
          float dq = sm.redd[t * 4 + q]; int kq = sm.redk[t * 4 + q];
          if (dq < bd || (dq == bd && kq < bk)) { bd = dq; bk = kq; }
        }
        cstorei(&ids[pbase + t], bk);
      }
    }
    gbar(flags, gen); ++gen;

    // ---- phase B: D-split segment-sum (32 pgroups x 8 dgroups), NT x loads ----
    {
      const int pg = b & 31, dg = b >> 5;
      for (int i = t; i < NK * PAD; i += NTHR) sc.accB[i] = 0.f;
      if (t < NK) cntB[t] = 0;
      idslB[t] = cloadi(&ids[pg * 1024 + t]);
      __syncthreads();
      const int id = idslB[t];
      if (dg == 0) atomicAdd(&cntB[id], 1);
      const float* xr = x + ((size_t)pg * 1024 + t) * DIM + dg * 32;
      f4v v0 = __builtin_nontemporal_load((const f4v*)xr + 0);
      f4v v1 = __builtin_nontemporal_load((const f4v*)xr + 1);
      f4v v2 = __builtin_nontemporal_load((const f4v*)xr + 2);
      f4v v3 = __builtin_nontemporal_load((const f4v*)xr + 3);
      f4v v4 = __builtin_nontemporal_load((const f4v*)xr + 4);
      f4v v5 = __builtin_nontemporal_load((const f4v*)xr + 5);
      f4v v6 = __builtin_nontemporal_load((const f4v*)xr + 6);
      f4v v7 = __builtin_nontemporal_load((const f4v*)xr + 7);
      float* ab = &sc.accB[id * PAD];
      atomicAdd(ab + 0,  v0[0]); atomicAdd(ab + 1,  v0[1]); atomicAdd(ab + 2,  v0[2]); atomicAdd(ab + 3,  v0[3]);
      atomicAdd(ab + 4,  v1[0]); atomicAdd(ab + 5,  v1[1]); atomicAdd(ab + 6,  v1[2]); atomicAdd(ab + 7,  v1[3]);
      atomicAdd(ab + 8,  v2[0]); atomicAdd(ab + 9,  v2[1]); atomicAdd(ab + 10, v2[2]); atomicAdd(ab + 11, v2[3]);
      atomicAdd(ab + 12, v3[0]); atomicAdd(ab + 13, v3[1]); atomicAdd(ab + 14, v3[2]); atomicAdd(ab + 15, v3[3]);
      atomicAdd(ab + 16, v4[0]); atomicAdd(ab + 17, v4[1]); atomicAdd(ab + 18, v4[2]); atomicAdd(ab + 19, v4[3]);
      atomicAdd(ab + 20, v5[0]); atomicAdd(ab + 21, v5[1]); atomicAdd(ab + 22, v5[2]); atomicAdd(ab + 23, v5[3]);
      atomicAdd(ab + 24, v6[0]); atomicAdd(ab + 25, v6[1]); atomicAdd(ab + 26, v6[2]); atomicAdd(ab + 27, v6[3]);
      atomicAdd(ab + 28, v7[0]); atomicAdd(ab + 29, v7[1]); atomicAdd(ab + 30, v7[2]); atomicAdd(ab + 31, v7[3]);
      __syncthreads();
#pragma unroll
      for (int s2 = 0; s2 < 4; ++s2) {
        int idx = s2 * NTHR + t;          // [0,4096)
        int k2 = idx >> 5, dl = idx & 31;
        cstore(&psum[(((size_t)dg * NK + k2) * 32 + pg) * 32 + dl], sc.accB[k2 * PAD + dl]);
      }
      if (dg == 0 && t < NK)
        cstore(&pcnt[(size_t)pg * NK + t], (float)cntB[t]);
    }
    gbar(flags, gen); ++gen;

    // ---- phase C: reduce partials -> means -> packed image + cn (128 blocks) ----
    if (b < NK) {
      const int k = b;
      const int hf = t >> 8, tt = t & 255;
      const int dgc = tt >> 5, dlc = tt & 31;
      float s = 0.f;
#pragma unroll
      for (int p2 = hf * 8; p2 < hf * 8 + 8; ++p2)
        s += cload(&psum[(((size_t)dgc * NK + k) * 32 + p2) * 32 + dlc]);
      sc.red4[hf * 256 + tt] = s;
      float cv = (t < 32) ? cload(&pcnt[(size_t)t * NK + k]) : 0.f;
      if (t < 64) {
#pragma unroll
        for (int m = 1; m < 32; m <<= 1) cv += __shfl_xor(cv, m, 64);
      }
      if (t == 0) cntsh = cv;
      __syncthreads();
      float eff = 0.f;
      if (t < DIM) {
        float mean = (sc.red4[t] + sc.red4[256 + t] + sc.red4[512 + t] + sc.red4[768 + t]) / cntsh;
        unsigned short hh = f2bf(mean);   // NaN if empty, as ref
        unsigned short ll = f2bf(mean - bf2f(hh));
        hsm[t] = hh; lsm[t] = ll;
        eff = bf2f(hh) + bf2f(ll);
      }
      __syncthreads();                    // red4 reads + hsm/lsm writes done
      sc.redcn[t] = (t < DIM) ? eff * eff : 0.f;
      if (t < NK) {
        ull_t wv = (ull_t)hsm[2 * t] | ((ull_t)lsm[2 * t] << 16)
                 | ((ull_t)hsm[2 * t + 1] << 32) | ((ull_t)lsm[2 * t + 1] << 48);
        cstore64(&cpk[(size_t)k * 128 + t], wv);
      }
      __syncthreads();
      for (int st = 512; st > 0; st >>= 1) { if (t < st) sc.redcn[t] += sc.redcn[t + st]; __syncthreads(); }
      if (t == 0) cstore(&cn[k], sc.redcn[0]);
    }
    gbar_pf(flags, gen, xhb, xlb, sm.bufs, t); ++gen;
  }

  // ---------------- final: loss (log-softmax + CE), deterministic reduce ----------------
  {
    f4v acc[2][2];
    gemm_core(sm, t, xhb, xlb, cpk, cn, acc);
#pragma unroll
    for (int i = 0; i < 2; ++i) {
#pragma unroll
      for (int r = 0; r < 4; ++r) {
        int prow = wr * 32 + i * 16 + g * 4 + r;
        float m = -1e30f;
#pragma unroll
        for (int j = 0; j < 2; ++j) m = fmaxf(m, acc[i][j][r]);
#pragma unroll
        for (int msk = 1; msk < 16; msk <<= 1) m = fmaxf(m, __shfl_xor(m, msk, 64));
        if (lr == 0) sm.redd[prow * 4 + wc] = m;
      }
    }
    __syncthreads();
    if (t < NK) {
      float m = sm.redd[t * 4];
#pragma unroll
      for (int q = 1; q < 4; ++q) m = fmaxf(m, sm.redd[t * 4 + q]);
      sm.gmaxs[t] = m;
      sm.labis[t] = cloadi(&ids[pbase + t]);
    }
    __syncthreads();
#pragma unroll
    for (int i = 0; i < 2; ++i) {
#pragma unroll
      for (int r = 0; r < 4; ++r) {
        int prow = wr * 32 + i * 16 + g * 4 + r;
        float m = sm.gmaxs[prow];
        int lab = sm.labis[prow];
        float s = 0.f;
#pragma unroll
        for (int j = 0; j < 2; ++j) {
          int col = wc * 32 + j * 16 + lr;
          float v = acc[i][j][r];
          s += expf(v - m);
          if (col == lab) sm.labvs[prow] = v;
        }
#pragma unroll
        for (int msk = 1; msk < 16; msk <<= 1) s += __shfl_xor(s, msk, 64);
        if (lr == 0) sm.redd[prow * 4 + wc] = s;
      }
    }
    __syncthreads();
    if (t < NK) {
      float se = sm.redd[t * 4] + sm.redd[t * 4 + 1] + sm.redd[t * 4 + 2] + sm.redd[t * 4 + 3];
      float lse = sm.gmaxs[t] + logf(se);
      sm.gmaxs[t] = lse - sm.labvs[t];
    }
    __syncthreads();
    if (t == 0) {
      float tot = 0.f;
      for (int q = 0; q < NK; ++q) tot += sm.gmaxs[q];
      cstore(&outp[b], tot);
    }
  }
  gbar(flags, gen); ++gen;
  if (b == 0) {
    sc.redcn[t] = (t < NBLK) ? cload(&outp[t]) : 0.f;
    __syncthreads();
    for (int s = 512; s > 0; s >>= 1) { if (t < s) sc.redcn[t] += sc.redcn[t + s]; __syncthreads(); }
    if (t == 0) out[0] = sc.redcn[0] * (1.0f / (float)NPTS);
  }
}

extern "C" void kernel_launch(void* const* d_in, const int* in_sizes, int n_in,
                              void* d_out, int out_size, void* d_ws, size_t ws_size,
                              hipStream_t stream) {
  const float* x        = (const float*)d_in[0];
  const int*   init_idx = (const int*)d_in[1];
  float* out = (float*)d_out;
  char* ws = (char*)d_ws;

  // ws layout (bytes):
  ushort_t* xh  = (ushort_t*)(ws);                    // 16777216
  ushort_t* xl  = (ushort_t*)(ws + 16777216);         // 16777216
  ull_t* cpk  = (ull_t*)(ws + 33554432);              // 128*128*8 = 131072
  float* cn   = (float*)(ws + 33685504);              // 512
  int*   ids  = (int*)(ws + 33686016);                // 131072
  float* psum = (float*)(ws + 33817088);              // 8*128*32*32*4 = 4194304
  float* pcnt = (float*)(ws + 38011392);              // 32*128*4 = 16384
  float* outp = (float*)(ws + 38027776);              // 1024
  unsigned* flags = (unsigned*)(ws + 38028800);       // 256*64B = 16384

  // reset barrier state every launch (graph replays include this node)
  hipMemsetAsync(flags, 0, 16384, stream);
  kmeans_fused<<<dim3(NBLK), dim3(NTHR), 0, stream>>>(
      x, init_idx, xh, xl, cpk, cn, ids, psum, pcnt, outp, flags, out);
}

// Round 11
// 7152.984 us; speedup vs baseline: 1.0136x; 1.0136x over previous
//
#include <hip/hip_runtime.h>
#include <cstdint>

#define NPTS 32768
#define DIM  256
#define NK   128
#define NITER 100
#define NBLK 256
#define NTHR 1024
#define PAD  33

typedef unsigned short ushort_t;
typedef unsigned long long ull_t;
typedef __attribute__((ext_vector_type(8))) short s8v;   // 8 bf16 in 4 VGPRs
typedef __attribute__((ext_vector_type(4))) float f4v;   // MFMA accumulator

__device__ __forceinline__ unsigned short f2bf(float f) {
  unsigned u = __float_as_uint(f);
  u += 0x7fffu + ((u >> 16) & 1u);      // RTNE
  return (unsigned short)(u >> 16);
}
__device__ __forceinline__ float bf2f(unsigned short b) {
  return __uint_as_float(((unsigned)b) << 16);
}

// agent-scope (LLC-coherent) accesses — bypass non-coherent L1/L2, so NO
// __threadfence is needed, and they do NOT evict the L2-resident xh/xl tiles.
__device__ __forceinline__ void cstore(float* p, float v) {
  __hip_atomic_store(p, v, __ATOMIC_RELAXED, __HIP_MEMORY_SCOPE_AGENT);
}
__device__ __forceinline__ float cload(const float* p) {
  return __hip_atomic_load(p, __ATOMIC_RELAXED, __HIP_MEMORY_SCOPE_AGENT);
}
__device__ __forceinline__ void cstorei(int* p, int v) {
  __hip_atomic_store(p, v, __ATOMIC_RELAXED, __HIP_MEMORY_SCOPE_AGENT);
}
__device__ __forceinline__ int cloadi(const int* p) {
  return __hip_atomic_load(p, __ATOMIC_RELAXED, __HIP_MEMORY_SCOPE_AGENT);
}
__device__ __forceinline__ void cstore64(ull_t* p, ull_t v) {
  __hip_atomic_store(p, v, __ATOMIC_RELAXED, __HIP_MEMORY_SCOPE_AGENT);
}
__device__ __forceinline__ ull_t cload64(const ull_t* p) {
  return __hip_atomic_load(p, __ATOMIC_RELAXED, __HIP_MEMORY_SCOPE_AGENT);
}
// 16B LLC-direct float4 load as two 8B agent-scope loads
__device__ __forceinline__ f4v cload128f(const ull_t* p) {
  ull_t a = cload64(p), b = cload64(p + 1);
  f4v r;
  r[0] = __uint_as_float((unsigned)a); r[1] = __uint_as_float((unsigned)(a >> 32));
  r[2] = __uint_as_float((unsigned)b); r[3] = __uint_as_float((unsigned)(b >> 32));
  return r;
}

// Stage one 32KB half-D x tile via global_load_lds (linear LDS dest,
// pre-swizzled global source). LDS[G] = global[G ^ (row&7)], 16B granules.
// Normal cache path: keeps xh/xl L2-resident (the ONLY L2 traffic).
__device__ __forceinline__ void stage4(const ushort_t* __restrict__ src, s8v* buf, int h, int t) {
  const int lane = t & 63;
  const int wb = (t >> 6) << 6;           // wave-uniform base granule
#pragma unroll
  for (int i = 0; i < 2; ++i) {
    const int Gb = i * 1024 + wb;
    const int G  = Gb + lane;
    const int Gs = G ^ ((G >> 4) & 7);
    const char* ga = (const char*)src + (G >> 4) * 512 + h * 256 + (Gs & 15) * 16;
    __builtin_amdgcn_global_load_lds(
        (const __attribute__((address_space(1))) void*)ga,
        (__attribute__((address_space(3))) void*)((char*)buf + Gb * 16),
        16, 0, 0);
  }
}

// Stage centroid hi/lo half-D tiles from the packed coherent image.
// cpk[k*128 + u] = dims {2u,2u+1}: hh0 | ll0<<16 | hh1<<32 | ll1<<48.
__device__ __forceinline__ void stage_c(const ull_t* __restrict__ cpk,
                                        s8v* bh, s8v* bl, int h, int t) {
#pragma unroll
  for (int i = 0; i < 2; ++i) {
    const int G = i * NTHR + t;           // granule id [0,2048)
    const int k = G >> 4, gcol = G & 15;
    const int sc2 = gcol ^ (k & 7);       // swizzled source column
    const ull_t* src = cpk + (size_t)k * 128 + h * 64 + sc2 * 4;
    ull_t w0 = cload64(src + 0), w1 = cload64(src + 1);
    ull_t w2 = cload64(src + 2), w3 = cload64(src + 3);
    s8v vh, vl;
    vh[0] = (short)w0; vl[0] = (short)(w0 >> 16); vh[1] = (short)(w0 >> 32); vl[1] = (short)(w0 >> 48);
    vh[2] = (short)w1; vl[2] = (short)(w1 >> 16); vh[3] = (short)(w1 >> 32); vl[3] = (short)(w1 >> 48);
    vh[4] = (short)w2; vl[4] = (short)(w2 >> 16); vh[5] = (short)(w2 >> 32); vl[5] = (short)(w2 >> 48);
    vh[6] = (short)w3; vl[6] = (short)(w3 >> 16); vh[7] = (short)(w3 >> 32); vl[7] = (short)(w3 >> 48);
    *(s8v*)((char*)bh + G * 16) = vh;
    *(s8v*)((char*)bl + G * 16) = vl;
  }
}

// ---- all-to-all 1-hop grid barrier (proven R9) ----
__device__ __forceinline__ void gbar(unsigned* flags, unsigned gen) {
  __syncthreads();
  if (threadIdx.x == 0)
    __hip_atomic_store(&flags[blockIdx.x * 16], gen, __ATOMIC_RELAXED, __HIP_MEMORY_SCOPE_AGENT);
  if (threadIdx.x < NBLK) {
    while (__hip_atomic_load(&flags[threadIdx.x * 16], __ATOMIC_RELAXED, __HIP_MEMORY_SCOPE_AGENT) < gen)
      __builtin_amdgcn_s_sleep(2);
  }
  asm volatile("" ::: "memory");
  __syncthreads();
}
// barrier that issues next GEMM's x half-0 DMA prefetch inside the window
__device__ __forceinline__ void gbar_pf(unsigned* flags, unsigned gen,
    const ushort_t* xhb, const ushort_t* xlb, s8v (*bufs)[2048], int t) {
  __syncthreads();
  stage4(xhb, bufs[0], 0, t);             // own immutable tile: race-free
  stage4(xlb, bufs[1], 0, t);
  if (t == 0)
    __hip_atomic_store(&flags[blockIdx.x * 16], gen, __ATOMIC_RELAXED, __HIP_MEMORY_SCOPE_AGENT);
  if (t < NBLK) {
    while (__hip_atomic_load(&flags[t * 16], __ATOMIC_RELAXED, __HIP_MEMORY_SCOPE_AGENT) < gen)
      __builtin_amdgcn_s_sleep(2);
  }
  asm volatile("" ::: "memory");
  __syncthreads();
}

struct SMa {
  s8v bufs[4][2048];        // XH, XL, CH, CL half-D tiles, 32 KB each = 128 KB
  float cns[NK];
  float redd[NK * 4];
  int   redk[NK * 4];
  float gmaxs[NK];
  float labvs[NK];
  int   labis[NK];
};
union ScU {                 // phase-exclusive scratch (16.9 KB)
  float accB[NK * PAD];     // phase B accumulator
  float red4[1024];         // phase C: 8 x 128 dim-partials
  float redcn[1024];        // tree-reduce scratch (aliases red4; sequenced)
};

// 16-wave (4x4) 3-pass hi/lo bf16 MFMA GEMM: acc[i][j][r] = x_p . c_k.
// cns = cn2[2k] + cn2[2k+1] (two D-half ssq partials).
__device__ __forceinline__ void gemm_core(
    SMa& sm, int t,
    const ushort_t* __restrict__ xhb, const ushort_t* __restrict__ xlb,
    const ull_t* __restrict__ cpk, const float* __restrict__ cn2, f4v (&acc)[2][2]) {
  const int lane = t & 63;
  const int w    = t >> 6;
  const int wr   = w >> 2, wc = w & 3;    // 4x4 wave grid
  const int g    = lane >> 4, lr = lane & 15;

  if (t < NK) sm.cns[t] = cload(&cn2[2 * t]) + cload(&cn2[2 * t + 1]);

  const f4v zero = {0.f, 0.f, 0.f, 0.f};
#pragma unroll
  for (int i = 0; i < 2; ++i)
#pragma unroll
    for (int j = 0; j < 2; ++j) acc[i][j] = zero;

  const int swz = (lr & 7) << 4;
  int a_off[2], b_off[2];
#pragma unroll
  for (int i = 0; i < 2; ++i) a_off[i] = (wr * 32 + i * 16 + lr) * 256 + g * 16;
#pragma unroll
  for (int j = 0; j < 2; ++j) b_off[j] = (wc * 32 + j * 16 + lr) * 256 + g * 16;

  for (int h = 0; h < 2; ++h) {           // two D-halves of 128
    if (h == 1) {                         // issue DMA first for overlap
      stage4(xhb, sm.bufs[0], 1, t);
      stage4(xlb, sm.bufs[1], 1, t);
    }
    stage_c(cpk, sm.bufs[2], sm.bufs[3], h, t);
    __syncthreads();                      // DMA + cloads + ds_writes landed
#pragma unroll
    for (int kk = 0; kk < 4; ++kk) {      // K=128 per half, 4 steps of 32
      s8v ah[2], al[2], bh[2], bl[2];
#pragma unroll
      for (int i = 0; i < 2; ++i) {
        int o = (a_off[i] + kk * 64) ^ swz;
        ah[i] = *(const s8v*)((const char*)sm.bufs[0] + o);
        al[i] = *(const s8v*)((const char*)sm.bufs[1] + o);
      }
#pragma unroll
      for (int j = 0; j < 2; ++j) {
        int o = (b_off[j] + kk * 64) ^ swz;
        bh[j] = *(const s8v*)((const char*)sm.bufs[2] + o);
        bl[j] = *(const s8v*)((const char*)sm.bufs[3] + o);
      }
#pragma unroll
      for (int i = 0; i < 2; ++i)
#pragma unroll
        for (int j = 0; j < 2; ++j) {
          acc[i][j] = __builtin_amdgcn_mfma_f32_16x16x32_bf16(ah[i], bh[j], acc[i][j], 0, 0, 0);
          acc[i][j] = __builtin_amdgcn_mfma_f32_16x16x32_bf16(ah[i], bl[j], acc[i][j], 0, 0, 0);
          acc[i][j] = __builtin_amdgcn_mfma_f32_16x16x32_bf16(al[i], bh[j], acc[i][j], 0, 0, 0);
        }
    }
    if (h == 0) __syncthreads();          // half-0 reads done before overwrite
  }
}

__global__ __launch_bounds__(NTHR, 1) void kmeans_fused(
    const float* __restrict__ x, const int* __restrict__ init_idx,
    ushort_t* __restrict__ xh, ushort_t* __restrict__ xl,
    ull_t* __restrict__ cpk, float* __restrict__ cn2, int* __restrict__ ids,
    float* __restrict__ psum, float* __restrict__ pcnt,
    float* __restrict__ outp, unsigned* __restrict__ flags,
    float* __restrict__ out) {
  __shared__ SMa sm;
  __shared__ ScU sc;
  __shared__ int idslB[1024];
  __shared__ int cntB[NK];
  __shared__ ushort_t hsm[DIM], lsm[DIM];
  __shared__ float cntsh;

  const int b = blockIdx.x;
  const int t = threadIdx.x;
  const int lane = t & 63;
  const int w  = t >> 6;
  const int wr = w >> 2, wc = w & 3;
  const int g  = lane >> 4, lr = lane & 15;
  const int pbase = b * 128;
  const ushort_t* xhb = xh + (size_t)pbase * DIM;
  const ushort_t* xlb = xl + (size_t)pbase * DIM;
  unsigned gen = 1;

  // ---------------- prep: x -> bf16 hi/lo images (own tile only) ----------------
  for (int i = 0; i < 4; ++i) {
    int gg = b * 4096 + i * NTHR + t;
    const float4* src = (const float4*)x + gg * 2;
    float4 fa = src[0], fb = src[1];
    float vv[8] = {fa.x, fa.y, fa.z, fa.w, fb.x, fb.y, fb.z, fb.w};
    s8v vh, vl;
#pragma unroll
    for (int j = 0; j < 8; ++j) {
      unsigned short hh = f2bf(vv[j]);
      vh[j] = (short)hh;
      vl[j] = (short)f2bf(vv[j] - bf2f(hh));
    }
    ((s8v*)xh)[gg] = vh;
    ((s8v*)xl)[gg] = vl;
  }

  // ---------------- init: c0 = x[init_idx] -> packed image + cn2 ----------------
  if (b < NK) {
    float eff = 0.f;
    if (t < DIM) {
      float v = x[init_idx[b] * DIM + t];
      unsigned short hh = f2bf(v);
      unsigned short ll = f2bf(v - bf2f(hh));
      hsm[t] = hh; lsm[t] = ll;
      eff = bf2f(hh) + bf2f(ll);
    }
    __syncthreads();
    sc.redcn[t] = (t < DIM) ? eff * eff : 0.f;
    if (t < NK) {
      ull_t wv = (ull_t)hsm[2 * t] | ((ull_t)lsm[2 * t] << 16)
               | ((ull_t)hsm[2 * t + 1] << 32) | ((ull_t)lsm[2 * t + 1] << 48);
      cstore64(&cpk[(size_t)b * 128 + t], wv);
    }
    __syncthreads();
    for (int s = 512; s > 0; s >>= 1) { if (t < s) sc.redcn[t] += sc.redcn[t + s]; __syncthreads(); }
    if (t == 0) { cstore(&cn2[b * 2], sc.redcn[0]); cstore(&cn2[b * 2 + 1], 0.f); }
  }
  gbar_pf(flags, gen, xhb, xlb, sm.bufs, t); ++gen;

  // ---------------- main loop ----------------
  for (int it = 0; it < NITER; ++it) {
    // ---- phase A: assign; ids -> LLC ----
    {
      f4v acc[2][2];
      gemm_core(sm, t, xhb, xlb, cpk, cn2, acc);
#pragma unroll
      for (int i = 0; i < 2; ++i) {
#pragma unroll
        for (int r = 0; r < 4; ++r) {
          int prow = wr * 32 + i * 16 + g * 4 + r;
          float bd = 1e30f; int bk = 0;
#pragma unroll
          for (int j = 0; j < 2; ++j) {
            int col = wc * 32 + j * 16 + lr;
            float s = sm.cns[col] - 2.f * acc[i][j][r];
            if (s < bd || (s == bd && col < bk)) { bd = s; bk = col; }
          }
#pragma unroll
          for (int msk = 1; msk < 16; msk <<= 1) {
            float od = __shfl_xor(bd, msk, 64);
            int   ok = __shfl_xor(bk, msk, 64);
            if (od < bd || (od == bd && ok < bk)) { bd = od; bk = ok; }
          }
          if (lr == 0) { sm.redd[prow * 4 + wc] = bd; sm.redk[prow * 4 + wc] = bk; }
        }
      }
      __syncthreads();
      if (t < NK) {
        float bd = sm.redd[t * 4]; int bk = sm.redk[t * 4];
#pragma unroll
        for (int q = 1; q < 4; ++q) {
          float dq = sm.redd[t * 4 + q]; int kq = sm.redk[t * 4 + q];
          if (dq < bd || (dq == bd && kq < bk)) { bd = dq; bk = kq; }
        }
        cstorei(&ids[pbase + t], bk);
      }
    }
    gbar(flags, gen); ++gen;

    // ---- phase B: D-split segment-sum (32 pgroups x 8 dgroups), LLC-direct x ----
    {
      const int pg = b & 31, dg = b >> 5;
      for (int i = t; i < NK * PAD; i += NTHR) sc.accB[i] = 0.f;
      if (t < NK) cntB[t] = 0;
      idslB[t] = cloadi(&ids[pg * 1024 + t]);
      __syncthreads();
      const int id = idslB[t];
      if (dg == 0) atomicAdd(&cntB[id], 1);
      const ull_t* xr = (const ull_t*)(x + ((size_t)pg * 1024 + t) * DIM + dg * 32);
      f4v v0 = cload128f(xr + 0);
      f4v v1 = cload128f(xr + 2);
      f4v v2 = cload128f(xr + 4);
      f4v v3 = cload128f(xr + 6);
      f4v v4 = cload128f(xr + 8);
      f4v v5 = cload128f(xr + 10);
      f4v v6 = cload128f(xr + 12);
      f4v v7 = cload128f(xr + 14);
      float* ab = &sc.accB[id * PAD];
      atomicAdd(ab + 0,  v0[0]); atomicAdd(ab + 1,  v0[1]); atomicAdd(ab + 2,  v0[2]); atomicAdd(ab + 3,  v0[3]);
      atomicAdd(ab + 4,  v1[0]); atomicAdd(ab + 5,  v1[1]); atomicAdd(ab + 6,  v1[2]); atomicAdd(ab + 7,  v1[3]);
      atomicAdd(ab + 8,  v2[0]); atomicAdd(ab + 9,  v2[1]); atomicAdd(ab + 10, v2[2]); atomicAdd(ab + 11, v2[3]);
      atomicAdd(ab + 12, v3[0]); atomicAdd(ab + 13, v3[1]); atomicAdd(ab + 14, v3[2]); atomicAdd(ab + 15, v3[3]);
      atomicAdd(ab + 16, v4[0]); atomicAdd(ab + 17, v4[1]); atomicAdd(ab + 18, v4[2]); atomicAdd(ab + 19, v4[3]);
      atomicAdd(ab + 20, v5[0]); atomicAdd(ab + 21, v5[1]); atomicAdd(ab + 22, v5[2]); atomicAdd(ab + 23, v5[3]);
      atomicAdd(ab + 24, v6[0]); atomicAdd(ab + 25, v6[1]); atomicAdd(ab + 26, v6[2]); atomicAdd(ab + 27, v6[3]);
      atomicAdd(ab + 28, v7[0]); atomicAdd(ab + 29, v7[1]); atomicAdd(ab + 30, v7[2]); atomicAdd(ab + 31, v7[3]);
      __syncthreads();
#pragma unroll
      for (int s2 = 0; s2 < 4; ++s2) {
        int idx = s2 * NTHR + t;          // [0,4096)
        int k2 = idx >> 5, dl = idx & 31;
        cstore(&psum[(((size_t)dg * NK + k2) * 32 + pg) * 32 + dl], sc.accB[k2 * PAD + dl]);
      }
      if (dg == 0 && t < NK)
        cstore(&pcnt[(size_t)pg * NK + t], (float)cntB[t]);
    }
    gbar_pf(flags, gen, xhb, xlb, sm.bufs, t); ++gen;   // prefetch next A's x half-0

    // ---- phase C: 256 blocks = 128 clusters x 2 D-halves ----
    {
      const int k = b >> 1, hh2 = b & 1;
      const int dwh = t & 127, pch = t >> 7;   // dim-in-half [0,128), pgroup chunk [0,8)
      const int dgc = hh2 * 4 + (dwh >> 5), dlc = dwh & 31;
      float s = 0.f;
#pragma unroll
      for (int p2 = pch * 4; p2 < pch * 4 + 4; ++p2)
        s += cload(&psum[(((size_t)dgc * NK + k) * 32 + p2) * 32 + dlc]);
      sc.red4[pch * 128 + dwh] = s;
      float cv = (t < 32) ? cload(&pcnt[(size_t)t * NK + k]) : 0.f;
      if (t < 64) {
#pragma unroll
        for (int m = 1; m < 32; m <<= 1) cv += __shfl_xor(cv, m, 64);
      }
      if (t == 0) cntsh = cv;
      __syncthreads();
      float eff = 0.f;
      if (t < 128) {
        float ssum = 0.f;
#pragma unroll
        for (int ww = 0; ww < 8; ++ww) ssum += sc.red4[ww * 128 + t];
        float mean = ssum / cntsh;        // NaN if empty, as ref
        unsigned short hh = f2bf(mean);
        unsigned short ll = f2bf(mean - bf2f(hh));
        hsm[t] = hh; lsm[t] = ll;
        eff = bf2f(hh) + bf2f(ll);
      }
      __syncthreads();                    // red4 reads + hsm/lsm writes done
      sc.redcn[t] = (t < 128) ? eff * eff : 0.f;
      if (t < 64) {
        ull_t wv = (ull_t)hsm[2 * t] | ((ull_t)lsm[2 * t] << 16)
                 | ((ull_t)hsm[2 * t + 1] << 32) | ((ull_t)lsm[2 * t + 1] << 48);
        cstore64(&cpk[(size_t)k * 128 + hh2 * 64 + t], wv);
      }
      __syncthreads();
      for (int st = 512; st > 0; st >>= 1) { if (t < st) sc.redcn[t] += sc.redcn[t + st]; __syncthreads(); }
      if (t == 0) cstore(&cn2[k * 2 + hh2], sc.redcn[0]);
    }
    gbar(flags, gen); ++gen;
  }

  // ---------------- final: loss (log-softmax + CE), deterministic reduce ----------------
  {
    f4v acc[2][2];
    gemm_core(sm, t, xhb, xlb, cpk, cn2, acc);
#pragma unroll
    for (int i = 0; i < 2; ++i) {
#pragma unroll
      for (int r = 0; r < 4; ++r) {
        int prow = wr * 32 + i * 16 + g * 4 + r;
        float m = -1e30f;
#pragma unroll
        for (int j = 0; j < 2; ++j) m = fmaxf(m, acc[i][j][r]);
#pragma unroll
        for (int msk = 1; msk < 16; msk <<= 1) m = fmaxf(m, __shfl_xor(m, msk, 64));
        if (lr == 0) sm.redd[prow * 4 + wc] = m;
      }
    }
    __syncthreads();
    if (t < NK) {
      float m = sm.redd[t * 4];
#pragma unroll
      for (int q = 1; q < 4; ++q) m = fmaxf(m, sm.redd[t * 4 + q]);
      sm.gmaxs[t] = m;
      sm.labis[t] = cloadi(&ids[pbase + t]);
    }
    __syncthreads();
#pragma unroll
    for (int i = 0; i < 2; ++i) {
#pragma unroll
      for (int r = 0; r < 4; ++r) {
        int prow = wr * 32 + i * 16 + g * 4 + r;
        float m = sm.gmaxs[prow];
        int lab = sm.labis[prow];
        float s = 0.f;
#pragma unroll
        for (int j = 0; j < 2; ++j) {
          int col = wc * 32 + j * 16 + lr;
          float v = acc[i][j][r];
          s += expf(v - m);
          if (col == lab) sm.labvs[prow] = v;
        }
#pragma unroll
        for (int msk = 1; msk < 16; msk <<= 1) s += __shfl_xor(s, msk, 64);
        if (lr == 0) sm.redd[prow * 4 + wc] = s;
      }
    }
    __syncthreads();
    if (t < NK) {
      float se = sm.redd[t * 4] + sm.redd[t * 4 + 1] + sm.redd[t * 4 + 2] + sm.redd[t * 4 + 3];
      float lse = sm.gmaxs[t] + logf(se);
      sm.gmaxs[t] = lse - sm.labvs[t];
    }
    __syncthreads();
    if (t == 0) {
      float tot = 0.f;
      for (int q = 0; q < NK; ++q) tot += sm.gmaxs[q];
      cstore(&outp[b], tot);
    }
  }
  gbar(flags, gen); ++gen;
  if (b == 0) {
    sc.redcn[t] = (t < NBLK) ? cload(&outp[t]) : 0.f;
    __syncthreads();
    for (int s = 512; s > 0; s >>= 1) { if (t < s) sc.redcn[t] += sc.redcn[t + s]; __syncthreads(); }
    if (t == 0) out[0] = sc.redcn[0] * (1.0f / (float)NPTS);
  }
}

extern "C" void kernel_launch(void* const* d_in, const int* in_sizes, int n_in,
                              void* d_out, int out_size, void* d_ws, size_t ws_size,
                              hipStream_t stream) {
  const float* x        = (const float*)d_in[0];
  const int*   init_idx = (const int*)d_in[1];
  float* out = (float*)d_out;
  char* ws = (char*)d_ws;

  // ws layout (bytes):
  ushort_t* xh  = (ushort_t*)(ws);                    // 16777216
  ushort_t* xl  = (ushort_t*)(ws + 16777216);         // 16777216
  ull_t* cpk  = (ull_t*)(ws + 33554432);              // 128*128*8 = 131072
  float* cn2  = (float*)(ws + 33685504);              // 128*2*4 = 1024
  int*   ids  = (int*)(ws + 33686528);                // 131072
  float* psum = (float*)(ws + 33817600);              // 8*128*32*32*4 = 4194304
  float* pcnt = (float*)(ws + 38011904);              // 32*128*4 = 16384
  float* outp = (float*)(ws + 38028288);              // 1024
  unsigned* flags = (unsigned*)(ws + 38029312);       // 256*64B = 16384

  // reset barrier state every launch (graph replays include this node)
  hipMemsetAsync(flags, 0, 16384, stream);
  kmeans_fused<<<dim3(NBLK), dim3(NTHR), 0, stream>>>(
      x, init_idx, xh, xl, cpk, cn2, ids, psum, pcnt, outp, flags, out);
}